// Round 6
// baseline (141.629 us; speedup 1.0000x reference)
//
#include <hip/hip_runtime.h>

// LogicGatedSNN for MI355X (gfx950) — round 6: TWO PURE-STREAM KERNELS.
//
// Rounds 1-5 post-mortem: three different fused structures all land at
// 139-149 us timed, moving 805 MB CU-side at ~5.8 TB/s (92% of the 6.3 TB/s
// copy ceiling). The shared structural feature is the per-row join: trace
// RMW fenced behind the row's syn scan + reduce. This round tests that
// directly by splitting:
//   K1: pure syn stream. wave-per-row, popc dot, butterfly reduce, writes
//       spikes/new_mem/new_thr (96 KB). No LDS, no barriers.
//   K2: pure trace RMW stream. block-per-row, NO reduction at all: reads
//       spike[o] (broadcast), x (L2-resident 32 KiB), tr; nt-stores new_trace.
// Stream ordering gives the K1->K2 dependency inside the captured graph.
//
// Exactness: integer popcount dot (any order bit-exact); scalar update path
// identical (__fmul_rn/__fadd_rn) to all passing rounds; phase-2 addend
// (x!=0 ? s : 0) == s*x exactly for s,x in {0,1}.
//
// Output layout (float32, flat): [spikes O][new_mem O][new_thr O][new_trace O*I]

constexpr int O_FEAT = 8192;
constexpr int I_FEAT = 8192;
constexpr float STATE_THR = 50.0f;

typedef float f32x4 __attribute__((ext_vector_type(4)));

// ---------------- K1: spikes = f(syn row, x); pure syn read stream ----------
__global__ __launch_bounds__(256) void snn_p1_spikes(
    const float* __restrict__ x,    // [I]
    const float* __restrict__ syn,  // [O*I]
    const float* __restrict__ mp,   // [O]
    const float* __restrict__ thr,  // [O]
    float* __restrict__ out)        // [3*O + O*I]
{
    const int lane = threadIdx.x & 63;
    const int o = (blockIdx.x * blockDim.x + threadIdx.x) >> 6;  // row = wave id
    const long long rowoff = (long long)o * I_FEAT;

    const f32x4* __restrict__ x4 = (const f32x4*)x;
    const f32x4* __restrict__ s4 = (const f32x4*)(syn + rowoff);

    const float mpv = mp[o];
    const float th  = thr[o];

    // 2048 f32x4 per row, 32 per lane. Pure syn stream + L2-resident x.
    int cnt = 0;
#pragma unroll 8
    for (int j = 0; j < 32; ++j) {
        const int idx = j * 64 + lane;
        const f32x4 sv = s4[idx];
        const f32x4 xv = x4[idx];
        const unsigned sn = (sv.x > STATE_THR ? 1u : 0u) | (sv.y > STATE_THR ? 2u : 0u)
                          | (sv.z > STATE_THR ? 4u : 0u) | (sv.w > STATE_THR ? 8u : 0u);
        const unsigned xn = (xv.x != 0.0f ? 1u : 0u) | (xv.y != 0.0f ? 2u : 0u)
                          | (xv.z != 0.0f ? 4u : 0u) | (xv.w != 0.0f ? 8u : 0u);
        cnt += __popc(sn & xn);  // exact integer
    }

    // Butterfly reduce: every lane holds the row total. No LDS, no barrier.
#pragma unroll
    for (int off = 1; off < 64; off <<= 1)
        cnt += __shfl_xor(cnt, off, 64);

    const float v_mem = __fadd_rn(__fmul_rn(mpv, 0.9f), (float)cnt);
    const float s = (v_mem >= th) ? 1.0f : 0.0f;
    if (lane == 0) {
        out[o] = s;
        out[O_FEAT + o] = __fmul_rn(__fmul_rn(v_mem, 1.0f - s), 0.1f);
        float nth = __fadd_rn(th, __fmul_rn(s - 0.1f, 0.1f));
        out[2 * O_FEAT + o] = fminf(fmaxf(nth, 1.0f), 20.0f);
    }
}

// ---------------- K2: new_trace = clip(tr*0.8 + s*x, 0, 5); pure RMW stream -
__global__ __launch_bounds__(256) void snn_p2_trace(
    const float* __restrict__ x,    // [I]
    const float* __restrict__ tr,   // [O*I]
    float* __restrict__ out)        // [3*O + O*I]; reads out[o] (spike)
{
    const int t = threadIdx.x;
    const int o = blockIdx.x;  // one block per row, zero reduction
    const long long rowoff = (long long)o * I_FEAT;

    const f32x4* __restrict__ x4 = (const f32x4*)x;
    const f32x4* __restrict__ t4 = (const f32x4*)(tr + rowoff);
    f32x4* __restrict__ n4 = (f32x4*)(out + 3LL * O_FEAT + rowoff);

    const float s = out[o];  // broadcast scalar load (written by K1)

#pragma unroll
    for (int j = 0; j < 8; ++j) {
        const int idx = j * 256 + t;
        const f32x4 tv = t4[idx];   // HBM/L3 stream
        const f32x4 xv = x4[idx];   // 32 KiB, L1/L2-resident
        f32x4 r;
        r.x = fminf(fmaxf(__fadd_rn(__fmul_rn(tv.x, 0.8f), (xv.x != 0.0f) ? s : 0.0f), 0.0f), 5.0f);
        r.y = fminf(fmaxf(__fadd_rn(__fmul_rn(tv.y, 0.8f), (xv.y != 0.0f) ? s : 0.0f), 0.0f), 5.0f);
        r.z = fminf(fmaxf(__fadd_rn(__fmul_rn(tv.z, 0.8f), (xv.z != 0.0f) ? s : 0.0f), 0.0f), 5.0f);
        r.w = fminf(fmaxf(__fadd_rn(__fmul_rn(tv.w, 0.8f), (xv.w != 0.0f) ? s : 0.0f), 0.0f), 5.0f);
        __builtin_nontemporal_store(r, &n4[idx]);
    }
}

extern "C" void kernel_launch(void* const* d_in, const int* in_sizes, int n_in,
                              void* d_out, int out_size, void* d_ws, size_t ws_size,
                              hipStream_t stream) {
    const float* x   = (const float*)d_in[0];  // spike_input [I]
    const float* syn = (const float*)d_in[1];  // synapse_states [O*I]
    const float* mp  = (const float*)d_in[2];  // membrane_potential [O]
    const float* th  = (const float*)d_in[3];  // adaptive_threshold [O]
    const float* tr  = (const float*)d_in[4];  // eligibility_trace [O*I]
    float* out = (float*)d_out;

    // K1: 1 wave/row, 4 rows per block -> 2048 blocks. K2: 1 block/row.
    snn_p1_spikes<<<O_FEAT / 4, 256, 0, stream>>>(x, syn, mp, th, out);
    snn_p2_trace<<<O_FEAT, 256, 0, stream>>>(x, tr, out);
}